// Round 9
// baseline (249.434 us; speedup 1.0000x reference)
//
#include <hip/hip_runtime.h>
#include <hip/hip_fp16.h>

// SoftNormalShader R6 (3rd resubmit; R6/R7/R8 benches lost to GPU-acquisition
// timeouts): two-phase split — pure-streaming weight pass + small
// gather/resolve pass through a 32B/pixel compact record.
// Rationale: R1-R5 all plateau at 2.0-2.4 TB/s regardless of structure;
// the invariant was a data-dependent gather serializing each wave's
// stream-consume chain. Phase 1 has ZERO gathers (copy-like), phase 2 is
// small and latency-tolerant.
// N=4, H=512, W=512, K=8, V=50000, F=100000

constexpr int   N_PIX      = 4 * 512 * 512;
constexpr int   N_FRAG     = N_PIX * 8;
constexpr float INV_SIGMA  = 1.0f / 1e-4f;
constexpr float INV_GAMMA  = 1.0f / 1e-4f;
constexpr float ZFARV      = 100.0f;
constexpr float INV_ZRANGE = 1.0f / 99.0f;   // 1/(ZFAR-ZNEAR)
constexpr float EPSV       = 1e-10f;

__device__ __forceinline__ uint pack_h2(float a, float b) {
    uint ua = (uint)__half_as_ushort(__float2half_rn(a));
    uint ub = (uint)__half_as_ushort(__float2half_rn(b));
    return ua | (ub << 16);
}
__device__ __forceinline__ float unp_lo(uint u) {
    return __half2float(__ushort_as_half((ushort)(u & 0xffffu)));
}
__device__ __forceinline__ float unp_hi(uint u) {
    return __half2float(__ushort_as_half((ushort)(u >> 16)));
}

// Prepass: gather vertex normals per face -> fp16, 9 halves in a 32B row.
// Table = F*32B = 3.2MB (L2-resident).
__global__ __launch_bounds__(256)
void build_face_normals_kernel(const float* __restrict__ vn,
                               const int*   __restrict__ faces,
                               __half*      __restrict__ fnh,
                               int nf)
{
    int f = blockIdx.x * blockDim.x + threadIdx.x;
    if (f >= nf) return;
    int v0 = faces[3 * f + 0];
    int v1 = faces[3 * f + 1];
    int v2 = faces[3 * f + 2];
    union { ushort us[16]; uint4 u4[2]; } row;
    row.us[0] = __half_as_ushort(__float2half(vn[3 * v0 + 0]));
    row.us[1] = __half_as_ushort(__float2half(vn[3 * v0 + 1]));
    row.us[2] = __half_as_ushort(__float2half(vn[3 * v0 + 2]));
    row.us[3] = __half_as_ushort(__float2half(vn[3 * v1 + 0]));
    row.us[4] = __half_as_ushort(__float2half(vn[3 * v1 + 1]));
    row.us[5] = __half_as_ushort(__float2half(vn[3 * v1 + 2]));
    row.us[6] = __half_as_ushort(__float2half(vn[3 * v2 + 0]));
    row.us[7] = __half_as_ushort(__float2half(vn[3 * v2 + 1]));
    row.us[8] = __half_as_ushort(__float2half(vn[3 * v2 + 2]));
    row.us[9] = 0; row.us[10] = 0; row.us[11] = 0;
    row.us[12] = 0; row.us[13] = 0; row.us[14] = 0; row.us[15] = 0;
    uint4* dst = reinterpret_cast<uint4*>(fnh + 16 * (size_t)f);
    dst[0] = row.u4[0];
    dst[1] = row.u4[1];
}

// ---------------- Phase 1: pure streaming, no gathers ----------------
// 2 lanes per pixel (k = 4h..4h+3). Emits per pixel (32B):
//  q0 = { base=delta*inv (f32), am=prod(1-pr) (f32), F0 (i32), F1 (i32) }
//  q1 = { h2(c00,c01), h2(c02,c10), h2(c11,c12), 0 }
// where c = w*inv*bary for the <=2 active fragments.
// F encoding: -1 = empty slot, F1 = -2 => >2 active, phase2 recomputes.
__global__ __launch_bounds__(256)
void p1_weights_kernel(const float4* __restrict__ bary4,
                       const float4* __restrict__ d4p,
                       const float4* __restrict__ z4p,
                       const int4*   __restrict__ f4p,
                       uint4*        __restrict__ slots)
{
    int gid = blockIdx.x * 256 + threadIdx.x;   // 2 threads per pixel
    int h   = gid & 1;

    float4 d4 = d4p[gid];
    float4 z4 = z4p[gid];
    int4   f4 = f4p[gid];
    const float4* bp = bary4 + 3 * (size_t)gid;
    float4 b0 = bp[0], b1 = bp[1], b2 = bp[2];

    float dk[4] = {d4.x, d4.y, d4.z, d4.w};
    float zk[4] = {z4.x, z4.y, z4.z, z4.w};
    int   fk[4] = {f4.x, f4.y, f4.z, f4.w};
    float bf[12] = {b0.x, b0.y, b0.z, b0.w, b1.x, b1.y, b1.z, b1.w,
                    b2.x, b2.y, b2.z, b2.w};

    float pr[4], zi[4];
#pragma unroll
    for (int k = 0; k < 4; ++k) {
        bool m = fk[k] >= 0;
        pr[k] = m ? __builtin_amdgcn_rcpf(1.0f + __expf(dk[k] * INV_SIGMA)) : 0.0f;
        zi[k] = m ? (ZFARV - zk[k]) * INV_ZRANGE : 0.0f;
    }

    float zmax = fmaxf(fmaxf(zi[0], zi[1]), fmaxf(zi[2], zi[3]));
    zmax = fmaxf(zmax, __shfl_xor(zmax, 1));

    float am = (1.0f - pr[0]) * (1.0f - pr[1]) * (1.0f - pr[2]) * (1.0f - pr[3]);
    am *= __shfl_xor(am, 1);

    float w[4];
#pragma unroll
    for (int k = 0; k < 4; ++k)
        w[k] = pr[k] * __expf((zi[k] - zmax) * INV_GAMMA);

    float ws = (w[0] + w[1]) + (w[2] + w[3]);
    ws += __shfl_xor(ws, 1);

    float delta = fmaxf(__expf((EPSV - zmax) * INV_GAMMA), EPSV);
    float inv   = __builtin_amdgcn_rcpf(ws + delta);
    float base  = delta * inv;

    // Local compaction of this lane's <=4 actives into <=2 slots.
    int   lf0 = -1, lf1 = -1, lcnt = 0;
    float c0x = 0.f, c0y = 0.f, c0z = 0.f;
    float c1x = 0.f, c1y = 0.f, c1z = 0.f;
#pragma unroll
    for (int k = 0; k < 4; ++k) {
        if (w[k] != 0.0f) {
            float cw = w[k] * inv;
            if (lcnt == 0) {
                lf0 = fk[k];
                c0x = cw * bf[3 * k + 0];
                c0y = cw * bf[3 * k + 1];
                c0z = cw * bf[3 * k + 2];
            } else if (lcnt == 1) {
                lf1 = fk[k];
                c1x = cw * bf[3 * k + 0];
                c1y = cw * bf[3 * k + 1];
                c1z = cw * bf[3 * k + 2];
            }
            ++lcnt;
        }
    }

    // Merge with partner lane (both lanes compute; h==0 writes).
    int   pcnt = __shfl_xor(lcnt, 1);
    int   pf0  = __shfl_xor(lf0, 1);
    int   pf1  = __shfl_xor(lf1, 1);
    float p0x = __shfl_xor(c0x, 1), p0y = __shfl_xor(c0y, 1), p0z = __shfl_xor(c0z, 1);
    float p1x = __shfl_xor(c1x, 1), p1y = __shfl_xor(c1y, 1), p1z = __shfl_xor(c1z, 1);

    int total = lcnt + pcnt;
    int   F0, F1;
    float S0x, S0y, S0z, S1x, S1y, S1z;
    if (lcnt == 0) {
        F0 = pf0; S0x = p0x; S0y = p0y; S0z = p0z;
        F1 = pf1; S1x = p1x; S1y = p1y; S1z = p1z;
    } else if (lcnt == 1) {
        F0 = lf0; S0x = c0x; S0y = c0y; S0z = c0z;
        F1 = pf0; S1x = p0x; S1y = p0y; S1z = p0z;   // pf0 may be -1
    } else {
        F0 = lf0; S0x = c0x; S0y = c0y; S0z = c0z;
        F1 = lf1; S1x = c1x; S1y = c1y; S1z = c1z;
    }
    if (total > 2) F1 = -2;   // overflow: phase2 recomputes this pixel

    if (h == 0) {
        int pix = gid >> 1;
        uint4 q0;
        q0.x = __float_as_uint(base);
        q0.y = __float_as_uint(am);
        q0.z = (uint)F0;
        q0.w = (uint)F1;
        uint4 q1;
        q1.x = pack_h2(S0x, S0y);
        q1.y = pack_h2(S0z, S1x);
        q1.z = pack_h2(S1y, S1z);
        q1.w = 0u;
        slots[2 * (size_t)pix + 0] = q0;
        slots[2 * (size_t)pix + 1] = q1;
    }
}

// ---------------- Phase 2: resolve (small, latency-tolerant) ----------------
__global__ __launch_bounds__(256)
void p2_resolve_kernel(const uint4*  __restrict__ slots,
                       const __half* __restrict__ fnh,
                       const float*  __restrict__ dists,
                       const float*  __restrict__ zbuf,
                       const int*    __restrict__ p2f,
                       const float*  __restrict__ bary,
                       float4*       __restrict__ out)
{
    int pix = blockIdx.x * 256 + threadIdx.x;
    if (pix >= N_PIX) return;

    uint4 q0 = slots[2 * (size_t)pix + 0];
    uint4 q1 = slots[2 * (size_t)pix + 1];
    float base = __uint_as_float(q0.x);
    float am   = __uint_as_float(q0.y);
    int   F0   = (int)q0.z;
    int   F1   = (int)q0.w;

    float r, g, b;

    if (F1 != -2) {
        r = base; g = base; b = base;
        if (F0 >= 0) {
            const __half* hp = fnh + 16 * (size_t)F0;
            uint4 a  = *reinterpret_cast<const uint4*>(hp);
            uint  b8 = reinterpret_cast<const uint*>(hp)[4];
            float2 n01 = __half22float2(*reinterpret_cast<const __half2*>(&a.x));
            float2 n23 = __half22float2(*reinterpret_cast<const __half2*>(&a.y));
            float2 n45 = __half22float2(*reinterpret_cast<const __half2*>(&a.z));
            float2 n67 = __half22float2(*reinterpret_cast<const __half2*>(&a.w));
            float2 n8x = __half22float2(*reinterpret_cast<const __half2*>(&b8));
            float cb0 = unp_lo(q1.x), cb1 = unp_hi(q1.x), cb2 = unp_lo(q1.y);
            r += cb0 * n01.x + cb1 * n23.y + cb2 * n67.x;
            g += cb0 * n01.y + cb1 * n45.x + cb2 * n67.y;
            b += cb0 * n23.x + cb1 * n45.y + cb2 * n8x.x;
        }
        if (F1 >= 0) {
            const __half* hp = fnh + 16 * (size_t)F1;
            uint4 a  = *reinterpret_cast<const uint4*>(hp);
            uint  b8 = reinterpret_cast<const uint*>(hp)[4];
            float2 n01 = __half22float2(*reinterpret_cast<const __half2*>(&a.x));
            float2 n23 = __half22float2(*reinterpret_cast<const __half2*>(&a.y));
            float2 n45 = __half22float2(*reinterpret_cast<const __half2*>(&a.z));
            float2 n67 = __half22float2(*reinterpret_cast<const __half2*>(&a.w));
            float2 n8x = __half22float2(*reinterpret_cast<const __half2*>(&b8));
            float cb0 = unp_hi(q1.y), cb1 = unp_lo(q1.z), cb2 = unp_hi(q1.z);
            r += cb0 * n01.x + cb1 * n23.y + cb2 * n67.x;
            g += cb0 * n01.y + cb1 * n45.x + cb2 * n67.y;
            b += cb0 * n23.x + cb1 * n45.y + cb2 * n8x.x;
        }
    } else {
        // Rare (~0.2%) overflow: recompute the whole pixel.
        float pr8[8], zi8[8], w8[8];
        int   ff8[8];
        float zmax = 0.0f;
        am = 1.0f;
#pragma unroll
        for (int k = 0; k < 8; ++k) {
            float d  = dists[8 * (size_t)pix + k];
            float zb = zbuf[8 * (size_t)pix + k];
            int   f  = p2f[8 * (size_t)pix + k];
            ff8[k] = f;
            bool m = f >= 0;
            pr8[k] = m ? __builtin_amdgcn_rcpf(1.0f + __expf(d * INV_SIGMA)) : 0.0f;
            zi8[k] = m ? (ZFARV - zb) * INV_ZRANGE : 0.0f;
            zmax   = fmaxf(zmax, zi8[k]);
            am    *= (1.0f - pr8[k]);
        }
        float ws = 0.0f;
#pragma unroll
        for (int k = 0; k < 8; ++k) {
            w8[k] = pr8[k] * __expf((zi8[k] - zmax) * INV_GAMMA);
            ws += w8[k];
        }
        float delta = fmaxf(__expf((EPSV - zmax) * INV_GAMMA), EPSV);
        float inv   = __builtin_amdgcn_rcpf(ws + delta);
        base = delta * inv;
        r = base; g = base; b = base;
#pragma unroll
        for (int k = 0; k < 8; ++k) {
            if (w8[k] != 0.0f) {
                float cw = w8[k] * inv;
                float bb0 = bary[24 * (size_t)pix + 3 * k + 0];
                float bb1 = bary[24 * (size_t)pix + 3 * k + 1];
                float bb2 = bary[24 * (size_t)pix + 3 * k + 2];
                const __half* hp = fnh + 16 * (size_t)ff8[k];
                uint4 a  = *reinterpret_cast<const uint4*>(hp);
                uint  b8v = reinterpret_cast<const uint*>(hp)[4];
                float2 n01 = __half22float2(*reinterpret_cast<const __half2*>(&a.x));
                float2 n23 = __half22float2(*reinterpret_cast<const __half2*>(&a.y));
                float2 n45 = __half22float2(*reinterpret_cast<const __half2*>(&a.z));
                float2 n67 = __half22float2(*reinterpret_cast<const __half2*>(&a.w));
                float2 n8x = __half22float2(*reinterpret_cast<const __half2*>(&b8v));
                r += cw * (bb0 * n01.x + bb1 * n23.y + bb2 * n67.x);
                g += cw * (bb0 * n01.y + bb1 * n45.x + bb2 * n67.y);
                b += cw * (bb0 * n23.x + bb1 * n45.y + bb2 * n8x.x);
            }
        }
    }

    float4 o;
    o.x = r; o.y = g; o.z = b; o.w = 1.0f - am;
    out[pix] = o;
}

// ---------------- Fallback (R5 single-kernel) if ws too small ----------------
__global__ __launch_bounds__(256)
void shade_fallback_kernel(const float*  __restrict__ bary,
                           const float*  __restrict__ dists,
                           const float*  __restrict__ zbuf,
                           const int*    __restrict__ p2f,
                           const __half* __restrict__ fnh,
                           float*        __restrict__ out)
{
    int gid = blockIdx.x * 256 + threadIdx.x;
    if (gid >= N_FRAG) return;
    int kk = gid & 7;
    float d  = dists[gid];
    float zb = zbuf[gid];
    int   f  = p2f[gid];
    float b0 = bary[3 * (size_t)gid + 0];
    float b1 = bary[3 * (size_t)gid + 1];
    float b2 = bary[3 * (size_t)gid + 2];
    bool  m  = f >= 0;
    float pr = m ? __builtin_amdgcn_rcpf(1.0f + __expf(d * INV_SIGMA)) : 0.0f;
    float zi = m ? (ZFARV - zb) * INV_ZRANGE : 0.0f;
    float zmax = zi;
    zmax = fmaxf(zmax, __shfl_xor(zmax, 1));
    zmax = fmaxf(zmax, __shfl_xor(zmax, 2));
    zmax = fmaxf(zmax, __shfl_xor(zmax, 4));
    float am = 1.0f - pr;
    am *= __shfl_xor(am, 1);
    am *= __shfl_xor(am, 2);
    am *= __shfl_xor(am, 4);
    float w  = pr * __expf((zi - zmax) * INV_GAMMA);
    int   fe = (w != 0.0f) ? f : 0;
    const __half* hp = fnh + 16 * (size_t)fe;
    uint4 a  = *reinterpret_cast<const uint4*>(hp);
    uint  b8 = reinterpret_cast<const uint*>(hp)[4];
    float2 n01 = __half22float2(*reinterpret_cast<const __half2*>(&a.x));
    float2 n23 = __half22float2(*reinterpret_cast<const __half2*>(&a.y));
    float2 n45 = __half22float2(*reinterpret_cast<const __half2*>(&a.z));
    float2 n67 = __half22float2(*reinterpret_cast<const __half2*>(&a.w));
    float2 n8x = __half22float2(*reinterpret_cast<const __half2*>(&b8));
    float cr = w * (b0 * n01.x + b1 * n23.y + b2 * n67.x);
    float cg = w * (b0 * n01.y + b1 * n45.x + b2 * n67.y);
    float cb = w * (b0 * n23.x + b1 * n45.y + b2 * n8x.x);
    float ws = w;
    ws += __shfl_xor(ws, 1);  cr += __shfl_xor(cr, 1);
    cg += __shfl_xor(cg, 1);  cb += __shfl_xor(cb, 1);
    ws += __shfl_xor(ws, 2);  cr += __shfl_xor(cr, 2);
    cg += __shfl_xor(cg, 2);  cb += __shfl_xor(cb, 2);
    ws += __shfl_xor(ws, 4);  cr += __shfl_xor(cr, 4);
    cg += __shfl_xor(cg, 4);  cb += __shfl_xor(cb, 4);
    if (kk == 0) {
        float delta     = fmaxf(__expf((EPSV - zmax) * INV_GAMMA), EPSV);
        float inv_denom = __builtin_amdgcn_rcpf(ws + delta);
        float4 o;
        o.x = (cr + delta) * inv_denom;
        o.y = (cg + delta) * inv_denom;
        o.z = (cb + delta) * inv_denom;
        o.w = 1.0f - am;
        reinterpret_cast<float4*>(out)[gid >> 3] = o;
    }
}

extern "C" void kernel_launch(void* const* d_in, const int* in_sizes, int n_in,
                              void* d_out, int out_size, void* d_ws, size_t ws_size,
                              hipStream_t stream) {
    const float* vn    = (const float*)d_in[0];
    const float* bary  = (const float*)d_in[1];
    const float* dists = (const float*)d_in[2];
    const float* zbuf  = (const float*)d_in[3];
    const int*   faces = (const int*)d_in[4];
    const int*   p2f   = (const int*)d_in[5];
    float*       out   = (float*)d_out;

    int nf = in_sizes[4] / 3;

    size_t table_bytes = (size_t)nf * 32;               // fp16 rows
    size_t slot_bytes  = (size_t)N_PIX * 32;            // 32B per pixel
    __half* fnh = (__half*)d_ws;

    build_face_normals_kernel<<<(nf + 255) / 256, 256, 0, stream>>>(vn, faces, fnh, nf);

    if (ws_size >= table_bytes + slot_bytes) {
        uint4* slots = (uint4*)((char*)d_ws + table_bytes);
        p1_weights_kernel<<<(N_PIX * 2) / 256, 256, 0, stream>>>(
            reinterpret_cast<const float4*>(bary),
            reinterpret_cast<const float4*>(dists),
            reinterpret_cast<const float4*>(zbuf),
            reinterpret_cast<const int4*>(p2f),
            slots);
        p2_resolve_kernel<<<N_PIX / 256, 256, 0, stream>>>(
            slots, fnh, dists, zbuf, p2f, bary,
            reinterpret_cast<float4*>(out));
    } else {
        shade_fallback_kernel<<<N_FRAG / 256, 256, 0, stream>>>(
            bary, dists, zbuf, p2f, fnh, out);
    }
}

// Round 10
// 227.010 us; speedup vs baseline: 1.0988x; 1.0988x over previous
//
#include <hip/hip_runtime.h>
#include <hip/hip_fp16.h>

// SoftNormalShader R10: single-pass, lane-per-fragment (empirical best, R2)
// + fp16-packed 32B face-normal table (R5) + conditional bary loads.
// R9's gather-free control kernel proved the 75-85us plateau is the
// platform's delivered-bytes rate (~2.9 TB/s touched) for this pattern,
// not kernel structure. So: minimize touched bytes, one pass.
// N=4, H=512, W=512, K=8, V=50000, F=100000

constexpr int   N_PIX      = 4 * 512 * 512;
constexpr int   N_FRAG     = N_PIX * 8;
constexpr float INV_SIGMA  = 1.0f / 1e-4f;
constexpr float INV_GAMMA  = 1.0f / 1e-4f;
constexpr float ZFARV      = 100.0f;
constexpr float INV_ZRANGE = 1.0f / 99.0f;   // 1/(ZFAR-ZNEAR)
constexpr float EPSV       = 1e-10f;

// Prepass: gather vertex normals per face -> fp16, 9 halves in a 32B row.
// Table = F*32B = 3.2MB (L2-resident). ~2us.
__global__ __launch_bounds__(256)
void build_face_normals_kernel(const float* __restrict__ vn,
                               const int*   __restrict__ faces,
                               __half*      __restrict__ fnh,
                               int nf)
{
    int f = blockIdx.x * blockDim.x + threadIdx.x;
    if (f >= nf) return;
    int v0 = faces[3 * f + 0];
    int v1 = faces[3 * f + 1];
    int v2 = faces[3 * f + 2];
    union { ushort us[16]; uint4 u4[2]; } row;
    row.us[0] = __half_as_ushort(__float2half(vn[3 * v0 + 0]));
    row.us[1] = __half_as_ushort(__float2half(vn[3 * v0 + 1]));
    row.us[2] = __half_as_ushort(__float2half(vn[3 * v0 + 2]));
    row.us[3] = __half_as_ushort(__float2half(vn[3 * v1 + 0]));
    row.us[4] = __half_as_ushort(__float2half(vn[3 * v1 + 1]));
    row.us[5] = __half_as_ushort(__float2half(vn[3 * v1 + 2]));
    row.us[6] = __half_as_ushort(__float2half(vn[3 * v2 + 0]));
    row.us[7] = __half_as_ushort(__float2half(vn[3 * v2 + 1]));
    row.us[8] = __half_as_ushort(__float2half(vn[3 * v2 + 2]));
    row.us[9] = 0; row.us[10] = 0; row.us[11] = 0;
    row.us[12] = 0; row.us[13] = 0; row.us[14] = 0; row.us[15] = 0;
    uint4* dst = reinterpret_cast<uint4*>(fnh + 16 * (size_t)f);
    dst[0] = row.u4[0];
    dst[1] = row.u4[1];
}

__global__ __launch_bounds__(256, 8)
void shade_kernel(const float*  __restrict__ bary,
                  const float*  __restrict__ dists,
                  const float*  __restrict__ zbuf,
                  const int*    __restrict__ p2f,
                  const __half* __restrict__ fnh,
                  float*        __restrict__ out)
{
    int gid = blockIdx.x * 256 + threadIdx.x;   // one lane per fragment
    int kk  = threadIdx.x & 7;                   // k within pixel

    // Dense coalesced streaming loads, 4B/lane each.
    float d  = dists[gid];
    float zb = zbuf[gid];
    int   f  = p2f[gid];

    bool  m  = f >= 0;
    // sigmoid(-d/sigma) = 1/(1+exp(d/sigma))
    float pr = m ? __builtin_amdgcn_rcpf(1.0f + __expf(d * INV_SIGMA)) : 0.0f;
    float zi = m ? (ZFARV - zb) * INV_ZRANGE : 0.0f;

    // 8-lane butterfly reductions (masks 1,2,4 stay inside the k-group).
    float zmax = zi;
    zmax = fmaxf(zmax, __shfl_xor(zmax, 1));
    zmax = fmaxf(zmax, __shfl_xor(zmax, 2));
    zmax = fmaxf(zmax, __shfl_xor(zmax, 4));

    float am = 1.0f - pr;           // alpha = prod(1 - prob)
    am *= __shfl_xor(am, 1);
    am *= __shfl_xor(am, 2);
    am *= __shfl_xor(am, 4);

    // Softmax weight; exp underflows to exactly 0 unless zi is within
    // ~0.0087 of zmax (gamma=1e-4) -> typically ~1 of 8 lanes active.
    float w = pr * __expf((zi - zmax) * INV_GAMMA);

    // bary + table gather ONLY for contributing fragments (saves ~45MB
    // of bary traffic; contribution of inactive lanes is exactly 0).
    float cr = 0.0f, cg = 0.0f, cb = 0.0f;
    if (w != 0.0f) {                 // implies m, so f >= 0
        float b0 = bary[3 * (size_t)gid + 0];
        float b1 = bary[3 * (size_t)gid + 1];
        float b2 = bary[3 * (size_t)gid + 2];
        const __half* hp = fnh + 16 * (size_t)f;
        uint4 a  = *reinterpret_cast<const uint4*>(hp);
        uint  u8 = reinterpret_cast<const uint*>(hp)[4];
        float2 n01 = __half22float2(*reinterpret_cast<const __half2*>(&a.x)); // n0x n0y
        float2 n23 = __half22float2(*reinterpret_cast<const __half2*>(&a.y)); // n0z n1x
        float2 n45 = __half22float2(*reinterpret_cast<const __half2*>(&a.z)); // n1y n1z
        float2 n67 = __half22float2(*reinterpret_cast<const __half2*>(&a.w)); // n2x n2y
        float2 n8x = __half22float2(*reinterpret_cast<const __half2*>(&u8));  // n2z --
        cr = w * (b0 * n01.x + b1 * n23.y + b2 * n67.x);
        cg = w * (b0 * n01.y + b1 * n45.x + b2 * n67.y);
        cb = w * (b0 * n23.x + b1 * n45.y + b2 * n8x.x);
    }

    // Sum reductions over the 8-lane group.
    float ws = w;
    ws += __shfl_xor(ws, 1);  cr += __shfl_xor(cr, 1);
    cg += __shfl_xor(cg, 1);  cb += __shfl_xor(cb, 1);
    ws += __shfl_xor(ws, 2);  cr += __shfl_xor(cr, 2);
    cg += __shfl_xor(cg, 2);  cb += __shfl_xor(cb, 2);
    ws += __shfl_xor(ws, 4);  cr += __shfl_xor(cr, 4);
    cg += __shfl_xor(cg, 4);  cb += __shfl_xor(cb, 4);

    if (kk == 0) {
        float delta     = fmaxf(__expf((EPSV - zmax) * INV_GAMMA), EPSV);
        float inv_denom = __builtin_amdgcn_rcpf(ws + delta);
        float4 o;
        o.x = (cr + delta) * inv_denom;   // background = (1,1,1)
        o.y = (cg + delta) * inv_denom;
        o.z = (cb + delta) * inv_denom;
        o.w = 1.0f - am;
        // 8 storing lanes per wave write contiguous float4 -> 128B/wave.
        reinterpret_cast<float4*>(out)[gid >> 3] = o;
    }
}

extern "C" void kernel_launch(void* const* d_in, const int* in_sizes, int n_in,
                              void* d_out, int out_size, void* d_ws, size_t ws_size,
                              hipStream_t stream) {
    const float* vn    = (const float*)d_in[0];
    const float* bary  = (const float*)d_in[1];
    const float* dists = (const float*)d_in[2];
    const float* zbuf  = (const float*)d_in[3];
    const int*   faces = (const int*)d_in[4];
    const int*   p2f   = (const int*)d_in[5];
    float*       out   = (float*)d_out;

    int nf = in_sizes[4] / 3;
    __half* fnh = (__half*)d_ws;   // nf*32B = 3.2MB; ws is at least this big

    build_face_normals_kernel<<<(nf + 255) / 256, 256, 0, stream>>>(vn, faces, fnh, nf);
    shade_kernel<<<N_FRAG / 256, 256, 0, stream>>>(bary, dists, zbuf, p2f, fnh, out);
}